// Round 10
// baseline (108.252 us; speedup 1.0000x reference)
//
#include <hip/hip_runtime.h>

#define NQ_ 30000
#define NC_ 16
#define C_  128
#define NS_ 8192
#define QB  16
#define NBLK (NQ_/QB)   // 1875

typedef __attribute__((ext_vector_type(4))) float  f32x4;
typedef __attribute__((ext_vector_type(8))) short  s16x8;

// workspace layout (float offsets)
#define WS_PART  0         // 16 cls * 16 chunks * 128 = 32768
#define WS_PCNT  32768     // 256
#define WS_T     33024     // 2048  (protos @ Wp + b1)
#define WS_PACK  35072     // shorts: W2frag[16384] Wqfrag[16384] pnfrag[2048]

__device__ inline short f2bf(float x){           // round-to-nearest-even bf16
  unsigned u = __float_as_uint(x);
  u += 0x7fffu + ((u >> 16) & 1u);
  return (short)(u >> 16);
}

// ---- kernel A: proto partial sums (blocks 0..255) + W2/Wq pack (blocks 256..287) ----
__global__ __launch_bounds__(128) void protoA(const float* __restrict__ sf,
                                              const int* __restrict__ lbl,
                                              const float* __restrict__ W1,
                                              const float* __restrict__ W2,
                                              float* __restrict__ ws){
  const int b = blockIdx.x;
  const int t = threadIdx.x;
  if (b < 256){
    const int cls = b >> 4;
    const int ch  = b & 15;
    const int r0  = ch * (NS_/16);
    float s = 0.f; int cnt = 0;
    #pragma unroll 4
    for (int r = r0; r < r0 + NS_/16; ++r){
      if (lbl[r] == cls){ s += sf[(size_t)r*C_ + t]; ++cnt; }
    }
    ws[WS_PART + (cls*16 + ch)*C_ + t] = s;
    if (t == 0) ws[WS_PCNT + cls*16 + ch] = (float)cnt;
  } else {
    // pack W2 (g<16384) / Wq (g>=16384) into MFMA B-fragment order
    short* packo = (short*)(ws + WS_PACK);
    const int g0 = (b - 256)*1024 + t*8;
    const int gg = g0 & 16383;
    const int ln = (gg >> 3) & 63, ks = (gg >> 9) & 3, wvv = gg >> 11;
    const int kb = ks*32 + ((ln >> 4) & 3)*8;
    const int col = wvv*16 + (ln & 15);
    const float* src = (g0 < 16384) ? W2 : W1;    // Wq = W1 rows [0,128)
    s16x8 v;
    #pragma unroll
    for (int i = 0; i < 8; ++i) v[i] = f2bf(src[(size_t)(kb + i)*C_ + col]);
    *(s16x8*)&packo[g0] = v;
  }
}

// ---- kernel B: per-class finalize + pn + tmat + pn-pack (16 blocks x 128 thr) ----
__global__ __launch_bounds__(128) void protoB(const float* __restrict__ W1,
                                              const float* __restrict__ b1,
                                              float* __restrict__ ws){
  __shared__ float pr[C_];
  __shared__ float rns;
  const int n = blockIdx.x;
  const int h = threadIdx.x;
  float s = 0.f;
  #pragma unroll
  for (int ch = 0; ch < 16; ++ch) s += ws[WS_PART + (n*16 + ch)*C_ + h];
  float cnt = 0.f;
  #pragma unroll
  for (int ch = 0; ch < 16; ++ch) cnt += ws[WS_PCNT + n*16 + ch];
  const float pv = (cnt > 0.f) ? s / fmaxf(cnt, 1.f) : 0.f;
  pr[h] = pv;
  __syncthreads();
  if (h < 64){
    float q = pr[h]*pr[h] + pr[h+64]*pr[h+64];
    q += __shfl_xor(q, 1);  q += __shfl_xor(q, 2);  q += __shfl_xor(q, 4);
    q += __shfl_xor(q, 8);  q += __shfl_xor(q, 16); q += __shfl_xor(q, 32);
    if (h == 0) rns = 1.f / fmaxf(sqrtf(q), 1e-8f);
  }
  __syncthreads();
  // pn-pack: thread h handles k=h for class n
  {
    short* packo = (short*)(ws + WS_PACK);
    const int k = h;
    const int gg = ((k >> 5)*64 + ((k >> 3) & 3)*16 + n)*8 + (k & 7);
    packo[32768 + gg] = f2bf(pv * rns);
  }
  // tmat: ws[WS_T + n*C_ + h] = b1[h] + sum_c pr[c]*W1[(C+c)*C+h]
  float acc = b1[h];
  #pragma unroll 8
  for (int c = 0; c < C_; ++c) acc = fmaf(pr[c], W1[(size_t)(C_ + c)*C_ + h], acc);
  ws[WS_T + n*C_ + h] = acc;
}

// ---- fused main: H regenerated in registers per wave; sim staged in LDS;
//      stores are linear dwordx4 (fill-kernel pattern). 256 thr, 3 blocks/CU. ----
__global__ __launch_bounds__(256, 3) void fused_main(const float* __restrict__ qfeat,
                                                     const float* __restrict__ W1,
                                                     const float* __restrict__ b2,
                                                     const float* __restrict__ ws,
                                                     float* __restrict__ out){
  __shared__ __align__(16) float simb[2*2*16*132];   // dbuf x 2 queries x [16][132]
  __shared__ float qw[QB][132];
  __shared__ float tl16[NC_][132];
  __shared__ float cosl[QB][NC_];
  __shared__ float rqn[QB];
  __shared__ float wcl[C_];

  float (*qfs)[132] = (float(*)[132])simb;   // prelude alias; dead before pair 0

  const int t    = threadIdx.x;
  const int lane = t & 63;
  const int wv   = t >> 6;          // 0..3
  const int fr   = lane & 15;
  const int fg   = lane >> 4;
  const int qbase = blockIdx.x * QB;
  float* out_cos = out + (size_t)NQ_ * NC_ * C_;
  const short* pack = (const short*)(ws + WS_PACK);

  // stage qf (16x128), t-matrix, Wc — all coalesced (8 dwords/thread each)
  {
    const int idx = t * 8, q = idx >> 7, c = idx & 127;
    *(f32x4*)&qfs[q][c]      = *(const f32x4*)(qfeat + (size_t)qbase*C_ + idx);
    *(f32x4*)&qfs[q][c+4]    = *(const f32x4*)(qfeat + (size_t)qbase*C_ + idx + 4);
    *(f32x4*)&tl16[q][c]     = *(const f32x4*)(ws + WS_T + idx);
    *(f32x4*)&tl16[q][c+4]   = *(const f32x4*)(ws + WS_T + idx + 4);
    if (t < 32) *(f32x4*)&wcl[t*4] = *(const f32x4*)(W1 + 2*C_*C_ + t*4);
  }
  __syncthreads();

  // 1/max(||q||, eps)
  if (t < 128){
    int q = t >> 3; int c0 = (t & 7) * 16;
    float s = 0.f;
    #pragma unroll
    for (int m = 0; m < 16; ++m){ float v = qfs[q][c0+m]; s = fmaf(v, v, s); }
    s += __shfl_xor(s, 1); s += __shfl_xor(s, 2); s += __shfl_xor(s, 4);
    if ((t & 7) == 0) rqn[q] = 1.f / fmaxf(sqrtf(s), 1e-8f);
  }

  // A-fragments of qf (row = query fr)
  s16x8 qfr[4];
  #pragma unroll
  for (int ks = 0; ks < 4; ++ks){
    const int c0 = ks*32 + fg*8;
    f32x4 a = *(const f32x4*)&qfs[fr][c0];
    f32x4 b = *(const f32x4*)&qfs[fr][c0+4];
    s16x8 v;
    v[0]=f2bf(a[0]); v[1]=f2bf(a[1]); v[2]=f2bf(a[2]); v[3]=f2bf(a[3]);
    v[4]=f2bf(b[0]); v[5]=f2bf(b[1]); v[6]=f2bf(b[2]); v[7]=f2bf(b[3]);
    qfr[ks] = v;
  }
  // B-fragments of W2 for this wave's two col-tiles
  s16x8 w2f[2][4];
  float b2v[2];
  #pragma unroll
  for (int j = 0; j < 2; ++j){
    const int tt = wv*2 + j;
    #pragma unroll
    for (int ks = 0; ks < 4; ++ks)
      w2f[j][ks] = *(const s16x8*)&pack[((tt*4 + ks)*64 + lane)*8];
    b2v[j] = b2[tt*16 + fr];
  }
  __syncthreads();   // rqn ready; all qfs reads done

  // qW = qf @ Wq : wave wv covers col-tiles wv*2, wv*2+1
  #pragma unroll
  for (int j = 0; j < 2; ++j){
    const int tt = wv*2 + j;
    f32x4 dq = {0.f,0.f,0.f,0.f};
    #pragma unroll
    for (int ks = 0; ks < 4; ++ks)
      dq = __builtin_amdgcn_mfma_f32_16x16x32_bf16(qfr[ks],
             *(const s16x8*)&pack[16384 + ((tt*4 + ks)*64 + lane)*8], dq, 0,0,0);
    #pragma unroll
    for (int r = 0; r < 4; ++r) qw[fg*4 + r][tt*16 + fr] = dq[r];
  }
  // cos = (qf @ pn^T) * rqn   (wave 0)
  if (wv == 0){
    f32x4 dc = {0.f,0.f,0.f,0.f};
    #pragma unroll
    for (int ks = 0; ks < 4; ++ks)
      dc = __builtin_amdgcn_mfma_f32_16x16x32_bf16(qfr[ks],
             *(const s16x8*)&pack[32768 + (ks*64 + lane)*8], dc, 0,0,0);
    #pragma unroll
    for (int r = 0; r < 4; ++r){
      const int q = fg*4 + r;
      const float cv = dc[r] * rqn[q];
      cosl[q][fr] = cv;
      out_cos[(size_t)(qbase + q)*NC_ + fr] = cv;
    }
  }
  __syncthreads();   // qw, cosl ready; qfs dead -> simb live

  // compute pair p: regenerate H frags in registers, MFMA, stage sim in LDS
  auto do_C = [&](int p){
    float* sb = simb + (p & 1) * (2*16*132);
    #pragma unroll
    for (int qq = 0; qq < 2; ++qq){
      const int q = p*2 + qq;
      const float cv = cosl[q][fr];
      s16x8 af[4];
      #pragma unroll
      for (int ks = 0; ks < 4; ++ks){
        const int k0 = ks*32 + fg*8;
        const f32x4 qa = *(const f32x4*)&qw[q][k0];     // broadcast (free)
        const f32x4 qb = *(const f32x4*)&qw[q][k0+4];
        const f32x4 ta = *(const f32x4*)&tl16[fr][k0];  // 2-way (free)
        const f32x4 tb = *(const f32x4*)&tl16[fr][k0+4];
        const f32x4 wa = *(const f32x4*)&wcl[k0];       // broadcast
        const f32x4 wb = *(const f32x4*)&wcl[k0+4];
        s16x8 v;
        #pragma unroll
        for (int jj = 0; jj < 4; ++jj)
          v[jj]   = f2bf(fmaxf(fmaf(cv, wa[jj], qa[jj] + ta[jj]), 0.f));
        #pragma unroll
        for (int jj = 0; jj < 4; ++jj)
          v[4+jj] = f2bf(fmaxf(fmaf(cv, wb[jj], qb[jj] + tb[jj]), 0.f));
        af[ks] = v;
      }
      #pragma unroll
      for (int j = 0; j < 2; ++j){
        f32x4 acc = {b2v[j], b2v[j], b2v[j], b2v[j]};
        acc = __builtin_amdgcn_mfma_f32_16x16x32_bf16(af[0], w2f[j][0], acc, 0,0,0);
        acc = __builtin_amdgcn_mfma_f32_16x16x32_bf16(af[1], w2f[j][1], acc, 0,0,0);
        acc = __builtin_amdgcn_mfma_f32_16x16x32_bf16(af[2], w2f[j][2], acc, 0,0,0);
        acc = __builtin_amdgcn_mfma_f32_16x16x32_bf16(af[3], w2f[j][3], acc, 0,0,0);
        const int ocol = (wv*2 + j)*16 + fr;
        #pragma unroll
        for (int r = 0; r < 4; ++r)
          sb[(qq*16 + fg*4 + r)*132 + ocol] = acc[r];   // 2-way (free)
      }
    }
  };

  // store pair p: perfectly linear dwordx4, thread t -> row t>>4, cols (t&15)*8..+8
  auto do_ST = [&](int p){
    const float* sb = simb + (p & 1) * (2*16*132);
    const int n = t >> 4, o = (t & 15) * 8;
    #pragma unroll
    for (int qq = 0; qq < 2; ++qq){
      const float* sp = &sb[(qq*16 + n)*132 + o];
      const f32x4 v0 = *(const f32x4*)sp;
      const f32x4 v1 = *(const f32x4*)(sp + 4);
      float* dst = out + (size_t)(qbase + p*2 + qq)*(NC_*C_) + n*C_ + o;
      *(f32x4*)dst       = v0;
      *(f32x4*)(dst + 4) = v1;
    }
  };

  do_C(0);
  __syncthreads();
  #pragma unroll
  for (int p = 1; p < 8; ++p){
    do_ST(p-1);      // stores issue first (latency hides under do_C's VALU/MFMA)
    do_C(p);         // writes buf[p&1] — opposite buffer from ST(p-1)
    __syncthreads();
  }
  do_ST(7);
}

extern "C" void kernel_launch(void* const* d_in, const int* in_sizes, int n_in,
                              void* d_out, int out_size, void* d_ws, size_t ws_size,
                              hipStream_t stream){
  const float* sf  = (const float*)d_in[0];
  const int*   lbl = (const int*)  d_in[1];
  const float* qf  = (const float*)d_in[2];
  const float* W1  = (const float*)d_in[3];
  const float* b1  = (const float*)d_in[4];
  const float* W2  = (const float*)d_in[5];
  const float* b2  = (const float*)d_in[6];
  float* ws  = (float*)d_ws;
  float* out = (float*)d_out;

  protoA<<<288, 128, 0, stream>>>(sf, lbl, W1, W2, ws);
  protoB<<<NC_, 128, 0, stream>>>(W1, b1, ws);
  fused_main<<<NBLK, 256, 0, stream>>>(qf, W1, b2, ws, out);
}

// Round 11
// 97.202 us; speedup vs baseline: 1.1137x; 1.1137x over previous
//
#include <hip/hip_runtime.h>

#define NQ_ 30000
#define NC_ 16
#define C_  128
#define NS_ 8192
#define QB  16
#define NBLK (NQ_/QB)   // 1875

typedef __attribute__((ext_vector_type(4))) float  f32x4;
typedef __attribute__((ext_vector_type(8))) short  s16x8;

// workspace layout (float offsets)
#define WS_PART  0         // 16 cls * 16 chunks * 128 = 32768
#define WS_PCNT  32768     // 256
#define WS_T     33024     // 2048  (protos @ Wp + b1)
#define WS_PACK  35072     // shorts: W2frag[16384] Wqfrag[16384] pnfrag[2048]

__device__ inline short f2bf(float x){           // round-to-nearest-even bf16
  unsigned u = __float_as_uint(x);
  u += 0x7fffu + ((u >> 16) & 1u);
  return (short)(u >> 16);
}

// ---- kernel A: proto partial sums (blocks 0..255) + W2/Wq pack (blocks 256..287) ----
__global__ __launch_bounds__(128) void protoA(const float* __restrict__ sf,
                                              const int* __restrict__ lbl,
                                              const float* __restrict__ W1,
                                              const float* __restrict__ W2,
                                              float* __restrict__ ws){
  const int b = blockIdx.x;
  const int t = threadIdx.x;
  if (b < 256){
    const int cls = b >> 4;
    const int ch  = b & 15;
    const int r0  = ch * (NS_/16);
    float s = 0.f; int cnt = 0;
    #pragma unroll 4
    for (int r = r0; r < r0 + NS_/16; ++r){
      if (lbl[r] == cls){ s += sf[(size_t)r*C_ + t]; ++cnt; }
    }
    ws[WS_PART + (cls*16 + ch)*C_ + t] = s;
    if (t == 0) ws[WS_PCNT + cls*16 + ch] = (float)cnt;
  } else {
    // pack W2 (g<16384) / Wq (g>=16384) into MFMA fragment order
    short* packo = (short*)(ws + WS_PACK);
    const int g0 = (b - 256)*1024 + t*8;
    const int gg = g0 & 16383;
    const int ln = (gg >> 3) & 63, ks = (gg >> 9) & 3, wvv = gg >> 11;
    const int kb = ks*32 + ((ln >> 4) & 3)*8;
    const int col = wvv*16 + (ln & 15);
    const float* src = (g0 < 16384) ? W2 : W1;    // Wq = W1 rows [0,128)
    s16x8 v;
    #pragma unroll
    for (int i = 0; i < 8; ++i) v[i] = f2bf(src[(size_t)(kb + i)*C_ + col]);
    *(s16x8*)&packo[g0] = v;
  }
}

// ---- kernel B: per-class finalize + pn + tmat + pn-pack (16 blocks x 128 thr) ----
__global__ __launch_bounds__(128) void protoB(const float* __restrict__ W1,
                                              const float* __restrict__ b1,
                                              float* __restrict__ ws){
  __shared__ float pr[C_];
  __shared__ float rns;
  const int n = blockIdx.x;
  const int h = threadIdx.x;
  float s = 0.f;
  #pragma unroll
  for (int ch = 0; ch < 16; ++ch) s += ws[WS_PART + (n*16 + ch)*C_ + h];
  float cnt = 0.f;
  #pragma unroll
  for (int ch = 0; ch < 16; ++ch) cnt += ws[WS_PCNT + n*16 + ch];
  const float pv = (cnt > 0.f) ? s / fmaxf(cnt, 1.f) : 0.f;
  pr[h] = pv;
  __syncthreads();
  if (h < 64){
    float q = pr[h]*pr[h] + pr[h+64]*pr[h+64];
    q += __shfl_xor(q, 1);  q += __shfl_xor(q, 2);  q += __shfl_xor(q, 4);
    q += __shfl_xor(q, 8);  q += __shfl_xor(q, 16); q += __shfl_xor(q, 32);
    if (h == 0) rns = 1.f / fmaxf(sqrtf(q), 1e-8f);
  }
  __syncthreads();
  // pn-pack: thread h handles k=h for class n
  {
    short* packo = (short*)(ws + WS_PACK);
    const int k = h;
    const int gg = ((k >> 5)*64 + ((k >> 3) & 3)*16 + n)*8 + (k & 7);
    packo[32768 + gg] = f2bf(pv * rns);
  }
  // tmat: ws[WS_T + n*C_ + h] = b1[h] + sum_c pr[c]*W1[(C+c)*C+h]
  float acc = b1[h];
  #pragma unroll 8
  for (int c = 0; c < C_; ++c) acc = fmaf(pr[c], W1[(size_t)(C_ + c)*C_ + h], acc);
  ws[WS_T + n*C_ + h] = acc;
}

// ---- fused main: R9 structure; phase-B operands SWAPPED -> transposed D tile
//      -> each thread stores one contiguous dwordx4 per tile (4x fewer store instrs) ----
__global__ __launch_bounds__(256, 4) void fused_main(const float* __restrict__ qfeat,
                                                     const float* __restrict__ W1,
                                                     const float* __restrict__ b2,
                                                     const float* __restrict__ ws,
                                                     float* __restrict__ out){
  __shared__ __align__(16) char un[16384];   // qfs[16][132] f32, then hfrag[4q*2048] bf16
  __shared__ float qw[QB][132];
  __shared__ float tl16[NC_][132];
  __shared__ float cosl[QB][NC_];
  __shared__ float rqn[QB];
  __shared__ float wcl[C_];

  float (*qfs)[132] = (float(*)[132])un;
  short* hfrag = (short*)un;

  const int t    = threadIdx.x;
  const int lane = t & 63;
  const int wv   = t >> 6;          // 0..3
  const int fr   = lane & 15;
  const int fg   = lane >> 4;
  const int qbase = blockIdx.x * QB;
  float* out_cos = out + (size_t)NQ_ * NC_ * C_;
  const short* pack = (const short*)(ws + WS_PACK);

  // stage qf (16x128), t-matrix, Wc — all coalesced (8 dwords/thread each)
  {
    const int idx = t * 8, q = idx >> 7, c = idx & 127;
    *(f32x4*)&qfs[q][c]      = *(const f32x4*)(qfeat + (size_t)qbase*C_ + idx);
    *(f32x4*)&qfs[q][c+4]    = *(const f32x4*)(qfeat + (size_t)qbase*C_ + idx + 4);
    *(f32x4*)&tl16[q][c]     = *(const f32x4*)(ws + WS_T + idx);
    *(f32x4*)&tl16[q][c+4]   = *(const f32x4*)(ws + WS_T + idx + 4);
    if (t < 32) *(f32x4*)&wcl[t*4] = *(const f32x4*)(W1 + 2*C_*C_ + t*4);
  }
  __syncthreads();

  // 1/max(||q||, eps)
  if (t < 128){
    int q = t >> 3; int c0 = (t & 7) * 16;
    float s = 0.f;
    #pragma unroll
    for (int m = 0; m < 16; ++m){ float v = qfs[q][c0+m]; s = fmaf(v, v, s); }
    s += __shfl_xor(s, 1); s += __shfl_xor(s, 2); s += __shfl_xor(s, 4);
    if ((t & 7) == 0) rqn[q] = 1.f / fmaxf(sqrtf(s), 1e-8f);
  }

  // A-fragments of qf (row = query fr)
  s16x8 qfr[4];
  #pragma unroll
  for (int ks = 0; ks < 4; ++ks){
    const int c0 = ks*32 + fg*8;
    f32x4 a = *(const f32x4*)&qfs[fr][c0];
    f32x4 b = *(const f32x4*)&qfs[fr][c0+4];
    s16x8 v;
    v[0]=f2bf(a[0]); v[1]=f2bf(a[1]); v[2]=f2bf(a[2]); v[3]=f2bf(a[3]);
    v[4]=f2bf(b[0]); v[5]=f2bf(b[1]); v[6]=f2bf(b[2]); v[7]=f2bf(b[3]);
    qfr[ks] = v;
  }
  // B-fragments of W2 for this wave's two col-tiles; b2 as f32x4 (transposed-D init)
  s16x8 w2f[2][4];
  f32x4 b2q[2];
  #pragma unroll
  for (int j = 0; j < 2; ++j){
    const int tt = wv*2 + j;
    #pragma unroll
    for (int ks = 0; ks < 4; ++ks)
      w2f[j][ks] = *(const s16x8*)&pack[((tt*4 + ks)*64 + lane)*8];
    b2q[j] = *(const f32x4*)&b2[tt*16 + fg*4];
  }
  __syncthreads();   // rqn ready; all qfs reads done

  // qW = qf @ Wq : wave wv covers col-tiles wv*2, wv*2+1
  #pragma unroll
  for (int j = 0; j < 2; ++j){
    const int tt = wv*2 + j;
    f32x4 dq = {0.f,0.f,0.f,0.f};
    #pragma unroll
    for (int ks = 0; ks < 4; ++ks)
      dq = __builtin_amdgcn_mfma_f32_16x16x32_bf16(qfr[ks],
             *(const s16x8*)&pack[16384 + ((tt*4 + ks)*64 + lane)*8], dq, 0,0,0);
    #pragma unroll
    for (int r = 0; r < 4; ++r) qw[fg*4 + r][tt*16 + fr] = dq[r];
  }
  // cos = (qf @ pn^T) * rqn   (wave 0)
  if (wv == 0){
    f32x4 dc = {0.f,0.f,0.f,0.f};
    #pragma unroll
    for (int ks = 0; ks < 4; ++ks)
      dc = __builtin_amdgcn_mfma_f32_16x16x32_bf16(qfr[ks],
             *(const s16x8*)&pack[32768 + (ks*64 + lane)*8], dc, 0,0,0);
    #pragma unroll
    for (int r = 0; r < 4; ++r){
      const int q = fg*4 + r;
      const float cv = dc[r] * rqn[q];
      cosl[q][fr] = cv;
      out_cos[(size_t)(qbase + q)*NC_ + fr] = cv;
    }
  }
  __syncthreads();   // qw, cosl ready; qfs dead -> hfrag live

  // phase-A constants: wave wv == k-step ksA; lane -> (class fr, k-group fg)
  const int k0 = wv*32 + fg*8;
  const f32x4 t8a = *(const f32x4*)&tl16[fr][k0];
  const f32x4 t8b = *(const f32x4*)&tl16[fr][k0+4];
  const f32x4 w8a = *(const f32x4*)&wcl[k0];
  const f32x4 w8b = *(const f32x4*)&wcl[k0+4];

  #pragma unroll
  for (int chunk = 0; chunk < 4; ++chunk){
    const int q0 = chunk * 4;
    // phase A: H = relu(qW + t_n + cos*Wc) -> bf16 fragments (full s16x8/thread/query)
    #pragma unroll
    for (int qq = 0; qq < 4; ++qq){
      const int q = q0 + qq;
      f32x4 qa = *(const f32x4*)&qw[q][k0];     // broadcast within fg-group
      f32x4 qb = *(const f32x4*)&qw[q][k0+4];
      const float cv = cosl[q][fr];
      s16x8 hv;
      #pragma unroll
      for (int jj = 0; jj < 4; ++jj)
        hv[jj] = f2bf(fmaxf(fmaf(cv, w8a[jj], qa[jj] + t8a[jj]), 0.f));
      #pragma unroll
      for (int jj = 0; jj < 4; ++jj)
        hv[4+jj] = f2bf(fmaxf(fmaf(cv, w8b[jj], qb[jj] + t8b[jj]), 0.f));
      *(s16x8*)&hfrag[qq*2048 + wv*512 + lane*8] = hv;   // b128, conflict-free
    }
    __syncthreads();
    // phase B: sim^T tiles via SWAPPED operands: D[o][n_c]
    //   thread holds o = tt*16+fg*4..+3 (consecutive), n_c = fr -> one dwordx4 store
    #pragma unroll
    for (int qq = 0; qq < 4; ++qq){
      const short* hb = &hfrag[qq*2048 + lane*8];
      s16x8 a0 = *(const s16x8*)&hb[0];
      s16x8 a1 = *(const s16x8*)&hb[512];
      s16x8 a2 = *(const s16x8*)&hb[1024];
      s16x8 a3 = *(const s16x8*)&hb[1536];
      const size_t qout = (size_t)(qbase + q0 + qq) * (NC_*C_);
      #pragma unroll
      for (int j = 0; j < 2; ++j){
        f32x4 acc = b2q[j];
        acc = __builtin_amdgcn_mfma_f32_16x16x32_bf16(w2f[j][0], a0, acc, 0,0,0);
        acc = __builtin_amdgcn_mfma_f32_16x16x32_bf16(w2f[j][1], a1, acc, 0,0,0);
        acc = __builtin_amdgcn_mfma_f32_16x16x32_bf16(w2f[j][2], a2, acc, 0,0,0);
        acc = __builtin_amdgcn_mfma_f32_16x16x32_bf16(w2f[j][3], a3, acc, 0,0,0);
        *(f32x4*)(out + qout + (size_t)fr*C_ + (wv*2 + j)*16 + fg*4) = acc;
      }
    }
    __syncthreads();
  }
}

extern "C" void kernel_launch(void* const* d_in, const int* in_sizes, int n_in,
                              void* d_out, int out_size, void* d_ws, size_t ws_size,
                              hipStream_t stream){
  const float* sf  = (const float*)d_in[0];
  const int*   lbl = (const int*)  d_in[1];
  const float* qf  = (const float*)d_in[2];
  const float* W1  = (const float*)d_in[3];
  const float* b1  = (const float*)d_in[4];
  const float* W2  = (const float*)d_in[5];
  const float* b2  = (const float*)d_in[6];
  float* ws  = (float*)d_ws;
  float* out = (float*)d_out;

  protoA<<<288, 128, 0, stream>>>(sf, lbl, W1, W2, ws);
  protoB<<<NC_, 128, 0, stream>>>(W1, b1, ws);
  fused_main<<<NBLK, 256, 0, stream>>>(qf, W1, b2, ws, out);
}

// Round 12
// 93.258 us; speedup vs baseline: 1.1608x; 1.0423x over previous
//
#include <hip/hip_runtime.h>

#define NQ_ 30000
#define NC_ 16
#define C_  128
#define NS_ 8192
#define QB  16
#define NBLK (NQ_/QB)   // 1875

typedef __attribute__((ext_vector_type(4))) float  f32x4;
typedef __attribute__((ext_vector_type(8))) short  s16x8;

// workspace layout (float offsets)
#define WS_PART  0         // 16 cls * 16 chunks * 128 = 32768
#define WS_PCNT  32768     // 256
#define WS_T     33024     // 2048  (protos @ Wp + b1)
#define WS_PACK  35072     // shorts: W2frag[16384] Wqfrag[16384] pnfrag[2048]

__device__ inline short f2bf(float x){           // round-to-nearest-even bf16
  unsigned u = __float_as_uint(x);
  u += 0x7fffu + ((u >> 16) & 1u);
  return (short)(u >> 16);
}

// ---- kernel A: proto partial sums (blocks 0..255) + W2/Wq pack (blocks 256..287) ----
__global__ __launch_bounds__(128) void protoA(const float* __restrict__ sf,
                                              const int* __restrict__ lbl,
                                              const float* __restrict__ W1,
                                              const float* __restrict__ W2,
                                              float* __restrict__ ws){
  const int b = blockIdx.x;
  const int t = threadIdx.x;
  if (b < 256){
    const int cls = b >> 4;
    const int ch  = b & 15;
    const int r0  = ch * (NS_/16);
    float s = 0.f; int cnt = 0;
    #pragma unroll 4
    for (int r = r0; r < r0 + NS_/16; ++r){
      if (lbl[r] == cls){ s += sf[(size_t)r*C_ + t]; ++cnt; }
    }
    ws[WS_PART + (cls*16 + ch)*C_ + t] = s;
    if (t == 0) ws[WS_PCNT + cls*16 + ch] = (float)cnt;
  } else {
    // pack W2 (g<16384) / Wq (g>=16384) into MFMA fragment order
    short* packo = (short*)(ws + WS_PACK);
    const int g0 = (b - 256)*1024 + t*8;
    const int gg = g0 & 16383;
    const int ln = (gg >> 3) & 63, ks = (gg >> 9) & 3, wvv = gg >> 11;
    const int kb = ks*32 + ((ln >> 4) & 3)*8;
    const int col = wvv*16 + (ln & 15);
    const float* src = (g0 < 16384) ? W2 : W1;    // Wq = W1 rows [0,128)
    s16x8 v;
    #pragma unroll
    for (int i = 0; i < 8; ++i) v[i] = f2bf(src[(size_t)(kb + i)*C_ + col]);
    *(s16x8*)&packo[g0] = v;
  }
}

// ---- kernel B: per-class finalize + pn + tmat + pn-pack (16 blocks x 128 thr) ----
__global__ __launch_bounds__(128) void protoB(const float* __restrict__ W1,
                                              const float* __restrict__ b1,
                                              float* __restrict__ ws){
  __shared__ float pr[C_];
  __shared__ float rns;
  const int n = blockIdx.x;
  const int h = threadIdx.x;
  float s = 0.f;
  #pragma unroll
  for (int ch = 0; ch < 16; ++ch) s += ws[WS_PART + (n*16 + ch)*C_ + h];
  float cnt = 0.f;
  #pragma unroll
  for (int ch = 0; ch < 16; ++ch) cnt += ws[WS_PCNT + n*16 + ch];
  const float pv = (cnt > 0.f) ? s / fmaxf(cnt, 1.f) : 0.f;
  pr[h] = pv;
  __syncthreads();
  if (h < 64){
    float q = pr[h]*pr[h] + pr[h+64]*pr[h+64];
    q += __shfl_xor(q, 1);  q += __shfl_xor(q, 2);  q += __shfl_xor(q, 4);
    q += __shfl_xor(q, 8);  q += __shfl_xor(q, 16); q += __shfl_xor(q, 32);
    if (h == 0) rns = 1.f / fmaxf(sqrtf(q), 1e-8f);
  }
  __syncthreads();
  // pn-pack: thread h handles k=h for class n
  {
    short* packo = (short*)(ws + WS_PACK);
    const int k = h;
    const int gg = ((k >> 5)*64 + ((k >> 3) & 3)*16 + n)*8 + (k & 7);
    packo[32768 + gg] = f2bf(pv * rns);
  }
  // tmat: ws[WS_T + n*C_ + h] = b1[h] + sum_c pr[c]*W1[(C+c)*C+h]
  float acc = b1[h];
  #pragma unroll 8
  for (int c = 0; c < C_; ++c) acc = fmaf(pr[c], W1[(size_t)(C_ + c)*C_ + h], acc);
  ws[WS_T + n*C_ + h] = acc;
}

// ---- fused main: wave-private queries, W2 in registers, ZERO main-loop barriers.
//      waves {0,1}: queries 0..7 (tiles 0-3 / 4-7); waves {2,3}: queries 8..15. ----
__global__ __launch_bounds__(256, 2) void fused_main(const float* __restrict__ qfeat,
                                                     const float* __restrict__ W1,
                                                     const float* __restrict__ b2,
                                                     const float* __restrict__ ws,
                                                     float* __restrict__ out){
  __shared__ __align__(16) float qfs[QB][132];
  __shared__ float qw[QB][132];
  __shared__ float tl16[NC_][132];
  __shared__ float cosl[QB][NC_];
  __shared__ float rqn[QB];

  const int t    = threadIdx.x;
  const int lane = t & 63;
  const int wv   = t >> 6;          // 0..3
  const int fr   = lane & 15;
  const int fg   = lane >> 4;
  const int qbase = blockIdx.x * QB;
  float* out_cos = out + (size_t)NQ_ * NC_ * C_;
  const short* pack = (const short*)(ws + WS_PACK);

  // stage qf (16x128), t-matrix — all coalesced (8 dwords/thread each)
  {
    const int idx = t * 8, q = idx >> 7, c = idx & 127;
    *(f32x4*)&qfs[q][c]      = *(const f32x4*)(qfeat + (size_t)qbase*C_ + idx);
    *(f32x4*)&qfs[q][c+4]    = *(const f32x4*)(qfeat + (size_t)qbase*C_ + idx + 4);
    *(f32x4*)&tl16[q][c]     = *(const f32x4*)(ws + WS_T + idx);
    *(f32x4*)&tl16[q][c+4]   = *(const f32x4*)(ws + WS_T + idx + 4);
  }
  __syncthreads();

  // 1/max(||q||, eps)
  if (t < 128){
    int q = t >> 3; int c0 = (t & 7) * 16;
    float s = 0.f;
    #pragma unroll
    for (int m = 0; m < 16; ++m){ float v = qfs[q][c0+m]; s = fmaf(v, v, s); }
    s += __shfl_xor(s, 1); s += __shfl_xor(s, 2); s += __shfl_xor(s, 4);
    if ((t & 7) == 0) rqn[q] = 1.f / fmaxf(sqrtf(s), 1e-8f);
  }

  // A-fragments of qf (row = query fr)
  s16x8 qfr[4];
  #pragma unroll
  for (int ks = 0; ks < 4; ++ks){
    const int c0 = ks*32 + fg*8;
    f32x4 a = *(const f32x4*)&qfs[fr][c0];
    f32x4 b = *(const f32x4*)&qfs[fr][c0+4];
    s16x8 v;
    v[0]=f2bf(a[0]); v[1]=f2bf(a[1]); v[2]=f2bf(a[2]); v[3]=f2bf(a[3]);
    v[4]=f2bf(b[0]); v[5]=f2bf(b[1]); v[6]=f2bf(b[2]); v[7]=f2bf(b[3]);
    qfr[ks] = v;
  }
  // per-lane constants for H-gen: t and Wc over ALL k-steps (lane class = fr)
  f32x4 t8[4][2], w8[4][2];
  #pragma unroll
  for (int ks = 0; ks < 4; ++ks){
    const int k0 = ks*32 + fg*8;
    t8[ks][0] = *(const f32x4*)&tl16[fr][k0];
    t8[ks][1] = *(const f32x4*)&tl16[fr][k0+4];
    w8[ks][0] = *(const f32x4*)(W1 + 2*C_*C_ + k0);
    w8[ks][1] = *(const f32x4*)(W1 + 2*C_*C_ + k0 + 4);
  }
  // this wave's 4 col-tiles of W2 in registers (+ b2)
  const int th = wv & 1;            // tile half: tiles th*4 .. th*4+3
  s16x8 w2f[4][4];
  float b2v[4];
  #pragma unroll
  for (int j = 0; j < 4; ++j){
    const int tt = th*4 + j;
    #pragma unroll
    for (int ks = 0; ks < 4; ++ks)
      w2f[j][ks] = *(const s16x8*)&pack[((tt*4 + ks)*64 + lane)*8];
    b2v[j] = b2[tt*16 + fr];
  }
  __syncthreads();   // rqn ready; all qfs reads done

  // qW = qf @ Wq : wave wv covers col-tiles wv*2, wv*2+1 (populates full qw[16][128])
  #pragma unroll
  for (int j = 0; j < 2; ++j){
    const int tt = wv*2 + j;
    f32x4 dq = {0.f,0.f,0.f,0.f};
    #pragma unroll
    for (int ks = 0; ks < 4; ++ks)
      dq = __builtin_amdgcn_mfma_f32_16x16x32_bf16(qfr[ks],
             *(const s16x8*)&pack[16384 + ((tt*4 + ks)*64 + lane)*8], dq, 0,0,0);
    #pragma unroll
    for (int r = 0; r < 4; ++r) qw[fg*4 + r][tt*16 + fr] = dq[r];
  }
  // cos = (qf @ pn^T) * rqn   (wave 0)
  if (wv == 0){
    f32x4 dc = {0.f,0.f,0.f,0.f};
    #pragma unroll
    for (int ks = 0; ks < 4; ++ks)
      dc = __builtin_amdgcn_mfma_f32_16x16x32_bf16(qfr[ks],
             *(const s16x8*)&pack[32768 + (ks*64 + lane)*8], dc, 0,0,0);
    #pragma unroll
    for (int r = 0; r < 4; ++r){
      const int q = fg*4 + r;
      const float cv = dc[r] * rqn[q];
      cosl[q][fr] = cv;
      out_cos[(size_t)(qbase + q)*NC_ + fr] = cv;
    }
  }
  __syncthreads();   // qw, cosl ready — LAST barrier

  // main loop: 8 wave-private queries, H in registers, stores never drained
  const int qg = (wv >> 1) * 8;     // query group base: 0 or 8
  for (int qq = 0; qq < 8; ++qq){
    const int q = qg + qq;
    const float cv = cosl[q][fr];
    s16x8 af[4];
    #pragma unroll
    for (int ks = 0; ks < 4; ++ks){
      const int k0 = ks*32 + fg*8;
      const f32x4 qa = *(const f32x4*)&qw[q][k0];    // broadcast, conflict-free
      const f32x4 qb = *(const f32x4*)&qw[q][k0+4];
      s16x8 v;
      #pragma unroll
      for (int jj = 0; jj < 4; ++jj)
        v[jj]   = f2bf(fmaxf(fmaf(cv, w8[ks][0][jj], qa[jj] + t8[ks][0][jj]), 0.f));
      #pragma unroll
      for (int jj = 0; jj < 4; ++jj)
        v[4+jj] = f2bf(fmaxf(fmaf(cv, w8[ks][1][jj], qb[jj] + t8[ks][1][jj]), 0.f));
      af[ks] = v;
    }
    const size_t qout = (size_t)(qbase + q) * (NC_*C_);
    #pragma unroll
    for (int j = 0; j < 4; ++j){
      f32x4 acc = {b2v[j], b2v[j], b2v[j], b2v[j]};
      acc = __builtin_amdgcn_mfma_f32_16x16x32_bf16(af[0], w2f[j][0], acc, 0,0,0);
      acc = __builtin_amdgcn_mfma_f32_16x16x32_bf16(af[1], w2f[j][1], acc, 0,0,0);
      acc = __builtin_amdgcn_mfma_f32_16x16x32_bf16(af[2], w2f[j][2], acc, 0,0,0);
      acc = __builtin_amdgcn_mfma_f32_16x16x32_bf16(af[3], w2f[j][3], acc, 0,0,0);
      const int ocol = (th*4 + j)*16 + fr;
      #pragma unroll
      for (int r = 0; r < 4; ++r)
        out[qout + (fg*4 + r)*C_ + ocol] = acc[r];
    }
  }
}

extern "C" void kernel_launch(void* const* d_in, const int* in_sizes, int n_in,
                              void* d_out, int out_size, void* d_ws, size_t ws_size,
                              hipStream_t stream){
  const float* sf  = (const float*)d_in[0];
  const int*   lbl = (const int*)  d_in[1];
  const float* qf  = (const float*)d_in[2];
  const float* W1  = (const float*)d_in[3];
  const float* b1  = (const float*)d_in[4];
  const float* W2  = (const float*)d_in[5];
  const float* b2  = (const float*)d_in[6];
  float* ws  = (float*)d_ws;
  float* out = (float*)d_out;

  protoA<<<288, 128, 0, stream>>>(sf, lbl, W1, W2, ws);
  protoB<<<NC_, 128, 0, stream>>>(W1, b1, ws);
  fused_main<<<NBLK, 256, 0, stream>>>(qf, W1, b2, ws, out);
}

// Round 13
// 89.306 us; speedup vs baseline: 1.2121x; 1.0443x over previous
//
#include <hip/hip_runtime.h>

#define NQ_ 30000
#define NC_ 16
#define C_  128
#define NS_ 8192
#define QB  16
#define NBLK (NQ_/QB)   // 1875

typedef __attribute__((ext_vector_type(4))) float  f32x4;
typedef __attribute__((ext_vector_type(8))) short  s16x8;

// workspace layout (float offsets)
#define WS_PART  0         // 16 cls * 16 chunks * 128 = 32768
#define WS_PCNT  32768     // 256
#define WS_T     33024     // 2048  (protos @ Wp + b1)
#define WS_PACK  35072     // shorts: W2frag[16384] Wqfrag[16384] pnfrag[2048]

__device__ inline short f2bf(float x){           // round-to-nearest-even bf16
  unsigned u = __float_as_uint(x);
  u += 0x7fffu + ((u >> 16) & 1u);
  return (short)(u >> 16);
}

// ---- kernel A: proto partial sums (blocks 0..255) + W2/Wq pack (blocks 256..287) ----
__global__ __launch_bounds__(128) void protoA(const float* __restrict__ sf,
                                              const int* __restrict__ lbl,
                                              const float* __restrict__ W1,
                                              const float* __restrict__ W2,
                                              float* __restrict__ ws){
  const int b = blockIdx.x;
  const int t = threadIdx.x;
  if (b < 256){
    const int cls = b >> 4;
    const int ch  = b & 15;
    const int r0  = ch * (NS_/16);
    float s = 0.f; int cnt = 0;
    #pragma unroll 4
    for (int r = r0; r < r0 + NS_/16; ++r){
      if (lbl[r] == cls){ s += sf[(size_t)r*C_ + t]; ++cnt; }
    }
    ws[WS_PART + (cls*16 + ch)*C_ + t] = s;
    if (t == 0) ws[WS_PCNT + cls*16 + ch] = (float)cnt;
  } else {
    // pack W2 (g<16384) / Wq (g>=16384) into MFMA fragment order
    short* packo = (short*)(ws + WS_PACK);
    const int g0 = (b - 256)*1024 + t*8;
    const int gg = g0 & 16383;
    const int ln = (gg >> 3) & 63, ks = (gg >> 9) & 3, wvv = gg >> 11;
    const int kb = ks*32 + ((ln >> 4) & 3)*8;
    const int col = wvv*16 + (ln & 15);
    const float* src = (g0 < 16384) ? W2 : W1;    // Wq = W1 rows [0,128)
    s16x8 v;
    #pragma unroll
    for (int i = 0; i < 8; ++i) v[i] = f2bf(src[(size_t)(kb + i)*C_ + col]);
    *(s16x8*)&packo[g0] = v;
  }
}

// ---- kernel B: per-class finalize + pn + tmat + pn-pack (16 blocks x 128 thr) ----
__global__ __launch_bounds__(128) void protoB(const float* __restrict__ W1,
                                              const float* __restrict__ b1,
                                              float* __restrict__ ws){
  __shared__ float pr[C_];
  __shared__ float rns;
  const int n = blockIdx.x;
  const int h = threadIdx.x;
  float s = 0.f;
  #pragma unroll
  for (int ch = 0; ch < 16; ++ch) s += ws[WS_PART + (n*16 + ch)*C_ + h];
  float cnt = 0.f;
  #pragma unroll
  for (int ch = 0; ch < 16; ++ch) cnt += ws[WS_PCNT + n*16 + ch];
  const float pv = (cnt > 0.f) ? s / fmaxf(cnt, 1.f) : 0.f;
  pr[h] = pv;
  __syncthreads();
  if (h < 64){
    float q = pr[h]*pr[h] + pr[h+64]*pr[h+64];
    q += __shfl_xor(q, 1);  q += __shfl_xor(q, 2);  q += __shfl_xor(q, 4);
    q += __shfl_xor(q, 8);  q += __shfl_xor(q, 16); q += __shfl_xor(q, 32);
    if (h == 0) rns = 1.f / fmaxf(sqrtf(q), 1e-8f);
  }
  __syncthreads();
  // pn-pack: thread h handles k=h for class n
  {
    short* packo = (short*)(ws + WS_PACK);
    const int k = h;
    const int gg = ((k >> 5)*64 + ((k >> 3) & 3)*16 + n)*8 + (k & 7);
    packo[32768 + gg] = f2bf(pv * rns);
  }
  // tmat: ws[WS_T + n*C_ + h] = b1[h] + sum_c pr[c]*W1[(C+c)*C+h]
  float acc = b1[h];
  #pragma unroll 8
  for (int c = 0; c < C_; ++c) acc = fmaf(pr[c], W1[(size_t)(C_ + c)*C_ + h], acc);
  ws[WS_T + n*C_ + h] = acc;
}

// ---- fused main: R9 structure; ONLY store path changed to full-128B-line stores
//      via wave-private LDS tile staging (no extra barriers). ----
__global__ __launch_bounds__(256, 4) void fused_main(const float* __restrict__ qfeat,
                                                     const float* __restrict__ W1,
                                                     const float* __restrict__ b2,
                                                     const float* __restrict__ ws,
                                                     float* __restrict__ out){
  __shared__ __align__(16) char un[16384];   // qfs[16][132] f32, then hfrag[4q*2048] bf16
  __shared__ float qw[QB][132];
  __shared__ __align__(16) float simw[4][16][40];   // per-wave 16x32 tile (+pad, 16B-aligned rows)
  __shared__ float cosl[QB][NC_];
  __shared__ float rqn[QB];
  __shared__ float wcl[C_];

  float (*qfs)[132] = (float(*)[132])un;
  short* hfrag = (short*)un;

  const int t    = threadIdx.x;
  const int lane = t & 63;
  const int wv   = t >> 6;          // 0..3
  const int fr   = lane & 15;
  const int fg   = lane >> 4;
  const int qbase = blockIdx.x * QB;
  float* out_cos = out + (size_t)NQ_ * NC_ * C_;
  const short* pack = (const short*)(ws + WS_PACK);

  // phase-A constants from global (L2-hot, replaces tl16 LDS array): lane class = fr
  const int k0 = wv*32 + fg*8;
  const f32x4 t8a = *(const f32x4*)(ws + WS_T + fr*C_ + k0);
  const f32x4 t8b = *(const f32x4*)(ws + WS_T + fr*C_ + k0 + 4);

  // stage qf (16x128), Wc — all coalesced (8 dwords/thread)
  {
    const int idx = t * 8, q = idx >> 7, c = idx & 127;
    *(f32x4*)&qfs[q][c]   = *(const f32x4*)(qfeat + (size_t)qbase*C_ + idx);
    *(f32x4*)&qfs[q][c+4] = *(const f32x4*)(qfeat + (size_t)qbase*C_ + idx + 4);
    if (t < 32) *(f32x4*)&wcl[t*4] = *(const f32x4*)(W1 + 2*C_*C_ + t*4);
  }
  __syncthreads();

  // 1/max(||q||, eps)
  if (t < 128){
    int q = t >> 3; int c0 = (t & 7) * 16;
    float s = 0.f;
    #pragma unroll
    for (int m = 0; m < 16; ++m){ float v = qfs[q][c0+m]; s = fmaf(v, v, s); }
    s += __shfl_xor(s, 1); s += __shfl_xor(s, 2); s += __shfl_xor(s, 4);
    if ((t & 7) == 0) rqn[q] = 1.f / fmaxf(sqrtf(s), 1e-8f);
  }

  // A-fragments of qf (row = query fr)
  s16x8 qfr[4];
  #pragma unroll
  for (int ks = 0; ks < 4; ++ks){
    const int c0 = ks*32 + fg*8;
    f32x4 a = *(const f32x4*)&qfs[fr][c0];
    f32x4 b = *(const f32x4*)&qfs[fr][c0+4];
    s16x8 v;
    v[0]=f2bf(a[0]); v[1]=f2bf(a[1]); v[2]=f2bf(a[2]); v[3]=f2bf(a[3]);
    v[4]=f2bf(b[0]); v[5]=f2bf(b[1]); v[6]=f2bf(b[2]); v[7]=f2bf(b[3]);
    qfr[ks] = v;
  }
  // B-fragments of W2 for this wave's two col-tiles
  s16x8 w2f[2][4];
  float b2v[2];
  #pragma unroll
  for (int j = 0; j < 2; ++j){
    const int tt = wv*2 + j;
    #pragma unroll
    for (int ks = 0; ks < 4; ++ks)
      w2f[j][ks] = *(const s16x8*)&pack[((tt*4 + ks)*64 + lane)*8];
    b2v[j] = b2[tt*16 + fr];
  }
  __syncthreads();   // rqn ready; all qfs reads done

  // qW = qf @ Wq : wave wv covers col-tiles wv*2, wv*2+1
  #pragma unroll
  for (int j = 0; j < 2; ++j){
    const int tt = wv*2 + j;
    f32x4 dq = {0.f,0.f,0.f,0.f};
    #pragma unroll
    for (int ks = 0; ks < 4; ++ks)
      dq = __builtin_amdgcn_mfma_f32_16x16x32_bf16(qfr[ks],
             *(const s16x8*)&pack[16384 + ((tt*4 + ks)*64 + lane)*8], dq, 0,0,0);
    #pragma unroll
    for (int r = 0; r < 4; ++r) qw[fg*4 + r][tt*16 + fr] = dq[r];
  }
  // cos = (qf @ pn^T) * rqn   (wave 0) — staged in cosl only, stored linearly below
  if (wv == 0){
    f32x4 dc = {0.f,0.f,0.f,0.f};
    #pragma unroll
    for (int ks = 0; ks < 4; ++ks)
      dc = __builtin_amdgcn_mfma_f32_16x16x32_bf16(qfr[ks],
             *(const s16x8*)&pack[32768 + (ks*64 + lane)*8], dc, 0,0,0);
    #pragma unroll
    for (int r = 0; r < 4; ++r){
      const int q = fg*4 + r;
      cosl[q][fr] = dc[r] * rqn[q];
    }
  }
  __syncthreads();   // qw, cosl ready; qfs dead -> hfrag live

  // linear cos store: 256 threads -> 1 KB contiguous (full 128-B lines)
  out_cos[(size_t)qbase*NC_ + t] = cosl[t >> 4][t & 15];

  const f32x4 w8a = *(const f32x4*)&wcl[k0];
  const f32x4 w8b = *(const f32x4*)&wcl[k0+4];

  #pragma unroll
  for (int chunk = 0; chunk < 4; ++chunk){
    const int q0 = chunk * 4;
    // phase A: H = relu(qW + t_n + cos*Wc) -> bf16 fragments (full s16x8/thread/query)
    #pragma unroll
    for (int qq = 0; qq < 4; ++qq){
      const int q = q0 + qq;
      f32x4 qa = *(const f32x4*)&qw[q][k0];     // broadcast within fg-group
      f32x4 qb = *(const f32x4*)&qw[q][k0+4];
      const float cv = cosl[q][fr];
      s16x8 hv;
      #pragma unroll
      for (int jj = 0; jj < 4; ++jj)
        hv[jj] = f2bf(fmaxf(fmaf(cv, w8a[jj], qa[jj] + t8a[jj]), 0.f));
      #pragma unroll
      for (int jj = 0; jj < 4; ++jj)
        hv[4+jj] = f2bf(fmaxf(fmaf(cv, w8b[jj], qb[jj] + t8b[jj]), 0.f));
      *(s16x8*)&hfrag[qq*2048 + wv*512 + lane*8] = hv;   // b128, conflict-free
    }
    __syncthreads();
    // phase B: sim = H @ W2 + b2; stage wave's 16x32 tile in LDS, then
    // 2 global dwordx4 per query covering 8 rows x 128 B FULL LINES each
    #pragma unroll
    for (int qq = 0; qq < 4; ++qq){
      const short* hb = &hfrag[qq*2048 + lane*8];
      s16x8 a0 = *(const s16x8*)&hb[0];
      s16x8 a1 = *(const s16x8*)&hb[512];
      s16x8 a2 = *(const s16x8*)&hb[1024];
      s16x8 a3 = *(const s16x8*)&hb[1536];
      #pragma unroll
      for (int j = 0; j < 2; ++j){
        f32x4 acc = {b2v[j], b2v[j], b2v[j], b2v[j]};
        acc = __builtin_amdgcn_mfma_f32_16x16x32_bf16(a0, w2f[j][0], acc, 0,0,0);
        acc = __builtin_amdgcn_mfma_f32_16x16x32_bf16(a1, w2f[j][1], acc, 0,0,0);
        acc = __builtin_amdgcn_mfma_f32_16x16x32_bf16(a2, w2f[j][2], acc, 0,0,0);
        acc = __builtin_amdgcn_mfma_f32_16x16x32_bf16(a3, w2f[j][3], acc, 0,0,0);
        #pragma unroll
        for (int r = 0; r < 4; ++r)
          simw[wv][fg*4 + r][j*16 + fr] = acc[r];   // wave-private, ~2-way banks
      }
      const size_t qout = (size_t)(qbase + q0 + qq) * (NC_*C_);
      #pragma unroll
      for (int g = 0; g < 2; ++g){
        const int row = g*8 + (lane >> 3);
        const f32x4 v = *(const f32x4*)&simw[wv][row][(lane & 7)*4];
        *(f32x4*)(out + qout + (size_t)row*C_ + wv*32 + (lane & 7)*4) = v;
      }
    }
    __syncthreads();
  }
}

extern "C" void kernel_launch(void* const* d_in, const int* in_sizes, int n_in,
                              void* d_out, int out_size, void* d_ws, size_t ws_size,
                              hipStream_t stream){
  const float* sf  = (const float*)d_in[0];
  const int*   lbl = (const int*)  d_in[1];
  const float* qf  = (const float*)d_in[2];
  const float* W1  = (const float*)d_in[3];
  const float* b1  = (const float*)d_in[4];
  const float* W2  = (const float*)d_in[5];
  const float* b2  = (const float*)d_in[6];
  float* ws  = (float*)d_ws;
  float* out = (float*)d_out;

  protoA<<<288, 128, 0, stream>>>(sf, lbl, W1, W2, ws);
  protoB<<<NC_, 128, 0, stream>>>(W1, b1, ws);
  fused_main<<<NBLK, 256, 0, stream>>>(qf, W1, b2, ws, out);
}

// Round 14
// 82.120 us; speedup vs baseline: 1.3182x; 1.0875x over previous
//
#include <hip/hip_runtime.h>

#define NQ_ 30000
#define NC_ 16
#define C_  128
#define NS_ 8192
#define QB  16
#define NBLK (NQ_/QB)   // 1875

typedef __attribute__((ext_vector_type(4))) float  f32x4;
typedef __attribute__((ext_vector_type(8))) short  s16x8;

// workspace layout (float offsets)
#define WS_PART  0         // 16 cls * 32 subchunks * 128 = 65536
#define WS_PCNT  65536     // 512
#define WS_T     66048     // 2048  (protos @ Wp + b1)
#define WS_PACK  68096     // shorts: W2frag[16384] Wqfrag[16384] pnfrag[2048]

__device__ inline short f2bf(float x){           // round-to-nearest-even bf16
  unsigned u = __float_as_uint(x);
  u += 0x7fffu + ((u >> 16) & 1u);
  return (short)(u >> 16);
}

// ---- kernel A: proto partial sums (blocks 0..255, labels via LDS, 2 row-subchunks)
//      + W2/Wq pack (blocks 256..271) ----
__global__ __launch_bounds__(256) void protoA(const float* __restrict__ sf,
                                              const int* __restrict__ lbl,
                                              const float* __restrict__ W1,
                                              const float* __restrict__ W2,
                                              float* __restrict__ ws){
  const int b = blockIdx.x;
  const int t = threadIdx.x;
  if (b < 256){
    __shared__ int ll[512];
    const int cls = b >> 4;
    const int ch  = b & 15;
    const int r0  = ch * 512;
    *(int2*)&ll[t*2] = *(const int2*)&lbl[r0 + t*2];   // one coalesced round-trip
    __syncthreads();
    const int sub = t >> 7;          // 0..1 : rows [sub*256, sub*256+256)
    const int c   = t & 127;
    const int i0  = sub * 256;
    float s0 = 0.f, s1 = 0.f; int cnt = 0;
    #pragma unroll 4
    for (int i = 0; i < 256; i += 2){
      if (ll[i0+i]   == cls){ s0 += sf[(size_t)(r0+i0+i  )*C_ + c]; ++cnt; }
      if (ll[i0+i+1] == cls){ s1 += sf[(size_t)(r0+i0+i+1)*C_ + c]; ++cnt; }
    }
    ws[WS_PART + ((size_t)(cls*32 + ch*2 + sub))*C_ + c] = s0 + s1;
    if (c == 0) ws[WS_PCNT + cls*32 + ch*2 + sub] = (float)cnt;
  } else {
    // pack W2 (g<16384) / Wq (g>=16384) into MFMA fragment order
    short* packo = (short*)(ws + WS_PACK);
    const int g0 = (b - 256)*2048 + t*8;     // 16 blocks x 2048 = 32768 exact
    const int gg = g0 & 16383;
    const int ln = (gg >> 3) & 63, ks = (gg >> 9) & 3, wvv = gg >> 11;
    const int kb = ks*32 + ((ln >> 4) & 3)*8;
    const int col = wvv*16 + (ln & 15);
    const float* src = (g0 < 16384) ? W2 : W1;    // Wq = W1 rows [0,128)
    s16x8 v;
    #pragma unroll
    for (int i = 0; i < 8; ++i) v[i] = f2bf(src[(size_t)(kb + i)*C_ + col]);
    *(s16x8*)&packo[g0] = v;
  }
}

// ---- kernel B: per-class finalize + pn + tmat + pn-pack (16 blocks x 128 thr) ----
__global__ __launch_bounds__(128) void protoB(const float* __restrict__ W1,
                                              const float* __restrict__ b1,
                                              float* __restrict__ ws){
  __shared__ float pr[C_];
  __shared__ float rns;
  const int n = blockIdx.x;
  const int h = threadIdx.x;
  float s = 0.f;
  #pragma unroll 8
  for (int ch = 0; ch < 32; ++ch) s += ws[WS_PART + ((size_t)(n*32 + ch))*C_ + h];
  float cnt = 0.f;
  #pragma unroll 8
  for (int ch = 0; ch < 32; ++ch) cnt += ws[WS_PCNT + n*32 + ch];
  const float pv = (cnt > 0.f) ? s / fmaxf(cnt, 1.f) : 0.f;
  pr[h] = pv;
  __syncthreads();
  if (h < 64){
    float q = pr[h]*pr[h] + pr[h+64]*pr[h+64];
    q += __shfl_xor(q, 1);  q += __shfl_xor(q, 2);  q += __shfl_xor(q, 4);
    q += __shfl_xor(q, 8);  q += __shfl_xor(q, 16); q += __shfl_xor(q, 32);
    if (h == 0) rns = 1.f / fmaxf(sqrtf(q), 1e-8f);
  }
  __syncthreads();
  // pn-pack: thread h handles k=h for class n
  {
    short* packo = (short*)(ws + WS_PACK);
    const int k = h;
    const int gg = ((k >> 5)*64 + ((k >> 3) & 3)*16 + n)*8 + (k & 7);
    packo[32768 + gg] = f2bf(pv * rns);
  }
  // tmat: ws[WS_T + n*C_ + h] = b1[h] + sum_c pr[c]*W1[(C+c)*C+h]
  float acc = b1[h];
  #pragma unroll 8
  for (int c = 0; c < C_; ++c) acc = fmaf(pr[c], W1[(size_t)(C_ + c)*C_ + h], acc);
  ws[WS_T + n*C_ + h] = acc;
}

// ---- fused main: byte-identical to R9 (88.4 us best), only WS constants differ ----
__global__ __launch_bounds__(256, 4) void fused_main(const float* __restrict__ qfeat,
                                                     const float* __restrict__ W1,
                                                     const float* __restrict__ b2,
                                                     const float* __restrict__ ws,
                                                     float* __restrict__ out){
  __shared__ __align__(16) char un[16384];   // qfs[16][132] f32, then hfrag[4q*2048] bf16
  __shared__ float qw[QB][132];
  __shared__ float tl16[NC_][132];
  __shared__ float cosl[QB][NC_];
  __shared__ float rqn[QB];
  __shared__ float wcl[C_];

  float (*qfs)[132] = (float(*)[132])un;
  short* hfrag = (short*)un;

  const int t    = threadIdx.x;
  const int lane = t & 63;
  const int wv   = t >> 6;          // 0..3
  const int fr   = lane & 15;
  const int fg   = lane >> 4;
  const int qbase = blockIdx.x * QB;
  float* out_cos = out + (size_t)NQ_ * NC_ * C_;
  const short* pack = (const short*)(ws + WS_PACK);

  // stage qf (16x128), t-matrix, Wc — all coalesced (8 dwords/thread each)
  {
    const int idx = t * 8, q = idx >> 7, c = idx & 127;
    *(f32x4*)&qfs[q][c]      = *(const f32x4*)(qfeat + (size_t)qbase*C_ + idx);
    *(f32x4*)&qfs[q][c+4]    = *(const f32x4*)(qfeat + (size_t)qbase*C_ + idx + 4);
    *(f32x4*)&tl16[q][c]     = *(const f32x4*)(ws + WS_T + idx);
    *(f32x4*)&tl16[q][c+4]   = *(const f32x4*)(ws + WS_T + idx + 4);
    if (t < 32) *(f32x4*)&wcl[t*4] = *(const f32x4*)(W1 + 2*C_*C_ + t*4);
  }
  __syncthreads();

  // 1/max(||q||, eps)
  if (t < 128){
    int q = t >> 3; int c0 = (t & 7) * 16;
    float s = 0.f;
    #pragma unroll
    for (int m = 0; m < 16; ++m){ float v = qfs[q][c0+m]; s = fmaf(v, v, s); }
    s += __shfl_xor(s, 1); s += __shfl_xor(s, 2); s += __shfl_xor(s, 4);
    if ((t & 7) == 0) rqn[q] = 1.f / fmaxf(sqrtf(s), 1e-8f);
  }

  // A-fragments of qf (row = query fr)
  s16x8 qfr[4];
  #pragma unroll
  for (int ks = 0; ks < 4; ++ks){
    const int c0 = ks*32 + fg*8;
    f32x4 a = *(const f32x4*)&qfs[fr][c0];
    f32x4 b = *(const f32x4*)&qfs[fr][c0+4];
    s16x8 v;
    v[0]=f2bf(a[0]); v[1]=f2bf(a[1]); v[2]=f2bf(a[2]); v[3]=f2bf(a[3]);
    v[4]=f2bf(b[0]); v[5]=f2bf(b[1]); v[6]=f2bf(b[2]); v[7]=f2bf(b[3]);
    qfr[ks] = v;
  }
  // B-fragments of W2 for this wave's two col-tiles
  s16x8 w2f[2][4];
  float b2v[2];
  #pragma unroll
  for (int j = 0; j < 2; ++j){
    const int tt = wv*2 + j;
    #pragma unroll
    for (int ks = 0; ks < 4; ++ks)
      w2f[j][ks] = *(const s16x8*)&pack[((tt*4 + ks)*64 + lane)*8];
    b2v[j] = b2[tt*16 + fr];
  }
  __syncthreads();   // rqn ready; all qfs reads done

  // qW = qf @ Wq : wave wv covers col-tiles wv*2, wv*2+1
  #pragma unroll
  for (int j = 0; j < 2; ++j){
    const int tt = wv*2 + j;
    f32x4 dq = {0.f,0.f,0.f,0.f};
    #pragma unroll
    for (int ks = 0; ks < 4; ++ks)
      dq = __builtin_amdgcn_mfma_f32_16x16x32_bf16(qfr[ks],
             *(const s16x8*)&pack[16384 + ((tt*4 + ks)*64 + lane)*8], dq, 0,0,0);
    #pragma unroll
    for (int r = 0; r < 4; ++r) qw[fg*4 + r][tt*16 + fr] = dq[r];
  }
  // cos = (qf @ pn^T) * rqn   (wave 0)
  if (wv == 0){
    f32x4 dc = {0.f,0.f,0.f,0.f};
    #pragma unroll
    for (int ks = 0; ks < 4; ++ks)
      dc = __builtin_amdgcn_mfma_f32_16x16x32_bf16(qfr[ks],
             *(const s16x8*)&pack[32768 + (ks*64 + lane)*8], dc, 0,0,0);
    #pragma unroll
    for (int r = 0; r < 4; ++r){
      const int q = fg*4 + r;
      const float cv = dc[r] * rqn[q];
      cosl[q][fr] = cv;
      out_cos[(size_t)(qbase + q)*NC_ + fr] = cv;
    }
  }
  __syncthreads();   // qw, cosl ready; qfs dead -> hfrag live

  // phase-A constants: wave wv == k-step ksA; lane -> (class fr, k-group fg)
  const int k0 = wv*32 + fg*8;
  const f32x4 t8a = *(const f32x4*)&tl16[fr][k0];
  const f32x4 t8b = *(const f32x4*)&tl16[fr][k0+4];
  const f32x4 w8a = *(const f32x4*)&wcl[k0];
  const f32x4 w8b = *(const f32x4*)&wcl[k0+4];

  #pragma unroll
  for (int chunk = 0; chunk < 4; ++chunk){
    const int q0 = chunk * 4;
    // phase A: H = relu(qW + t_n + cos*Wc) -> bf16 fragments (full s16x8/thread/query)
    #pragma unroll
    for (int qq = 0; qq < 4; ++qq){
      const int q = q0 + qq;
      f32x4 qa = *(const f32x4*)&qw[q][k0];     // broadcast within fg-group
      f32x4 qb = *(const f32x4*)&qw[q][k0+4];
      const float cv = cosl[q][fr];
      s16x8 hv;
      #pragma unroll
      for (int jj = 0; jj < 4; ++jj)
        hv[jj] = f2bf(fmaxf(fmaf(cv, w8a[jj], qa[jj] + t8a[jj]), 0.f));
      #pragma unroll
      for (int jj = 0; jj < 4; ++jj)
        hv[4+jj] = f2bf(fmaxf(fmaf(cv, w8b[jj], qb[jj] + t8b[jj]), 0.f));
      *(s16x8*)&hfrag[qq*2048 + wv*512 + lane*8] = hv;   // b128, conflict-free
    }
    __syncthreads();
    // phase B: sim = H @ W2 + b2 ; one ds_read set feeds both col-tiles
    #pragma unroll
    for (int qq = 0; qq < 4; ++qq){
      const short* hb = &hfrag[qq*2048 + lane*8];
      s16x8 a0 = *(const s16x8*)&hb[0];
      s16x8 a1 = *(const s16x8*)&hb[512];
      s16x8 a2 = *(const s16x8*)&hb[1024];
      s16x8 a3 = *(const s16x8*)&hb[1536];
      const size_t qout = (size_t)(qbase + q0 + qq) * (NC_*C_);
      #pragma unroll
      for (int j = 0; j < 2; ++j){
        f32x4 acc = {b2v[j], b2v[j], b2v[j], b2v[j]};
        acc = __builtin_amdgcn_mfma_f32_16x16x32_bf16(a0, w2f[j][0], acc, 0,0,0);
        acc = __builtin_amdgcn_mfma_f32_16x16x32_bf16(a1, w2f[j][1], acc, 0,0,0);
        acc = __builtin_amdgcn_mfma_f32_16x16x32_bf16(a2, w2f[j][2], acc, 0,0,0);
        acc = __builtin_amdgcn_mfma_f32_16x16x32_bf16(a3, w2f[j][3], acc, 0,0,0);
        const int ocol = (wv*2 + j)*16 + fr;
        #pragma unroll
        for (int r = 0; r < 4; ++r)
          out[qout + (fg*4 + r)*C_ + ocol] = acc[r];
      }
    }
    __syncthreads();
  }
}

extern "C" void kernel_launch(void* const* d_in, const int* in_sizes, int n_in,
                              void* d_out, int out_size, void* d_ws, size_t ws_size,
                              hipStream_t stream){
  const float* sf  = (const float*)d_in[0];
  const int*   lbl = (const int*)  d_in[1];
  const float* qf  = (const float*)d_in[2];
  const float* W1  = (const float*)d_in[3];
  const float* b1  = (const float*)d_in[4];
  const float* W2  = (const float*)d_in[5];
  const float* b2  = (const float*)d_in[6];
  float* ws  = (float*)d_ws;
  float* out = (float*)d_out;

  protoA<<<272, 256, 0, stream>>>(sf, lbl, W1, W2, ws);
  protoB<<<NC_, 128, 0, stream>>>(W1, b1, ws);
  fused_main<<<NBLK, 256, 0, stream>>>(qf, W1, b2, ws, out);
}

// Round 15
// 75.085 us; speedup vs baseline: 1.4417x; 1.0937x over previous
//
#include <hip/hip_runtime.h>

#define NQ_ 30000
#define NC_ 16
#define C_  128
#define NS_ 8192
#define QB2 32
#define NBLK2 ((NQ_ + QB2 - 1)/QB2)   // 938, last block half

typedef __attribute__((ext_vector_type(4))) float  f32x4;
typedef __attribute__((ext_vector_type(8))) short  s16x8;

// workspace layout (float offsets)
#define WS_PART  0         // 16 cls * 32 subchunks * 128 = 65536
#define WS_PCNT  65536     // 512
#define WS_T     66048     // 2048  (protos @ Wp + b1)
#define WS_PACK  68096     // shorts: W2frag[16384] Wqfrag[16384] pnfrag[2048]

__device__ inline short f2bf(float x){           // round-to-nearest-even bf16
  unsigned u = __float_as_uint(x);
  u += 0x7fffu + ((u >> 16) & 1u);
  return (short)(u >> 16);
}

// ---- kernel A: proto partial sums (blocks 0..255, labels via LDS, 2 row-subchunks)
//      + W2/Wq pack (blocks 256..271) ----
__global__ __launch_bounds__(256) void protoA(const float* __restrict__ sf,
                                              const int* __restrict__ lbl,
                                              const float* __restrict__ W1,
                                              const float* __restrict__ W2,
                                              float* __restrict__ ws){
  const int b = blockIdx.x;
  const int t = threadIdx.x;
  if (b < 256){
    __shared__ int ll[512];
    const int cls = b >> 4;
    const int ch  = b & 15;
    const int r0  = ch * 512;
    *(int2*)&ll[t*2] = *(const int2*)&lbl[r0 + t*2];   // one coalesced round-trip
    __syncthreads();
    const int sub = t >> 7;          // 0..1 : rows [sub*256, sub*256+256)
    const int c   = t & 127;
    const int i0  = sub * 256;
    float s0 = 0.f, s1 = 0.f; int cnt = 0;
    #pragma unroll 4
    for (int i = 0; i < 256; i += 2){
      if (ll[i0+i]   == cls){ s0 += sf[(size_t)(r0+i0+i  )*C_ + c]; ++cnt; }
      if (ll[i0+i+1] == cls){ s1 += sf[(size_t)(r0+i0+i+1)*C_ + c]; ++cnt; }
    }
    ws[WS_PART + ((size_t)(cls*32 + ch*2 + sub))*C_ + c] = s0 + s1;
    if (c == 0) ws[WS_PCNT + cls*32 + ch*2 + sub] = (float)cnt;
  } else {
    // pack W2 (g<16384) / Wq (g>=16384) into MFMA fragment order
    short* packo = (short*)(ws + WS_PACK);
    const int g0 = (b - 256)*2048 + t*8;     // 16 blocks x 2048 = 32768 exact
    const int gg = g0 & 16383;
    const int ln = (gg >> 3) & 63, ks = (gg >> 9) & 3, wvv = gg >> 11;
    const int kb = ks*32 + ((ln >> 4) & 3)*8;
    const int col = wvv*16 + (ln & 15);
    const float* src = (g0 < 16384) ? W2 : W1;    // Wq = W1 rows [0,128)
    s16x8 v;
    #pragma unroll
    for (int i = 0; i < 8; ++i) v[i] = f2bf(src[(size_t)(kb + i)*C_ + col]);
    *(s16x8*)&packo[g0] = v;
  }
}

// ---- kernel B: per-class finalize + pn-pack + tmat (16 blocks x 512 thr, 4-way c-split) ----
__global__ __launch_bounds__(512) void protoB(const float* __restrict__ W1,
                                              const float* __restrict__ b1,
                                              float* __restrict__ ws){
  __shared__ float pr[C_];
  __shared__ float sacc[4][C_];
  __shared__ float rns;
  const int n = blockIdx.x;
  const int t = threadIdx.x;
  const int h = t & 127;
  const int part = t >> 7;         // 0..3
  if (t < 128){
    float s = 0.f, cnt = 0.f;
    #pragma unroll 8
    for (int ch = 0; ch < 32; ++ch) s   += ws[WS_PART + ((size_t)(n*32 + ch))*C_ + h];
    #pragma unroll 8
    for (int ch = 0; ch < 32; ++ch) cnt += ws[WS_PCNT + n*32 + ch];
    pr[h] = (cnt > 0.f) ? s / fmaxf(cnt, 1.f) : 0.f;
  }
  __syncthreads();
  if (t < 64){
    float q = pr[t]*pr[t] + pr[t+64]*pr[t+64];
    q += __shfl_xor(q, 1);  q += __shfl_xor(q, 2);  q += __shfl_xor(q, 4);
    q += __shfl_xor(q, 8);  q += __shfl_xor(q, 16); q += __shfl_xor(q, 32);
    if (t == 0) rns = 1.f / fmaxf(sqrtf(q), 1e-8f);
  }
  // tmat partial: part p sums c in [p*32, p*32+32)  (pr ready after first sync)
  {
    float a = 0.f;
    const int c0 = part * 32;
    #pragma unroll 8
    for (int c = c0; c < c0 + 32; ++c) a = fmaf(pr[c], W1[(size_t)(C_ + c)*C_ + h], a);
    sacc[part][h] = a;
  }
  __syncthreads();   // rns + sacc ready
  if (t < 128){
    // pn-pack: thread h handles k=h for class n
    short* packo = (short*)(ws + WS_PACK);
    const int gg = ((h >> 5)*64 + ((h >> 3) & 3)*16 + n)*8 + (h & 7);
    packo[32768 + gg] = f2bf(pr[h] * rns);
    ws[WS_T + n*C_ + h] = b1[h] + ((sacc[0][h] + sacc[1][h]) + (sacc[2][h] + sacc[3][h]));
  }
}

// ---- fused main: R14 per-query structure, QB=32 (2 query groups of 16) ----
__global__ __launch_bounds__(256, 3) void fused_main(const float* __restrict__ qfeat,
                                                     const float* __restrict__ W1,
                                                     const float* __restrict__ b2,
                                                     const float* __restrict__ ws,
                                                     float* __restrict__ out){
  __shared__ __align__(16) char un[16896];   // qfs[32][132] f32 | hfrag[4q*2048] bf16
  __shared__ float qw[QB2][132];
  __shared__ float tl16[NC_][132];
  __shared__ float cosl[QB2][NC_];
  __shared__ float rqn[QB2];
  __shared__ float wcl[C_];

  float (*qfs)[132] = (float(*)[132])un;
  short* hfrag = (short*)un;

  const int t    = threadIdx.x;
  const int lane = t & 63;
  const int wv   = t >> 6;          // 0..3
  const int fr   = lane & 15;
  const int fg   = lane >> 4;
  const int qbase = blockIdx.x * QB2;
  float* out_cos = out + (size_t)NQ_ * NC_ * C_;
  const short* pack = (const short*)(ws + WS_PACK);

  // stage qf (32x128, row-clamped for tail block), t-matrix, Wc — all coalesced
  {
    const int q = t >> 3, c = (t & 7) * 16;
    int gr = qbase + q; if (gr > NQ_ - 1) gr = NQ_ - 1;
    const float* src = qfeat + (size_t)gr*C_ + c;
    *(f32x4*)&qfs[q][c]    = *(const f32x4*)(src);
    *(f32x4*)&qfs[q][c+4]  = *(const f32x4*)(src + 4);
    *(f32x4*)&qfs[q][c+8]  = *(const f32x4*)(src + 8);
    *(f32x4*)&qfs[q][c+12] = *(const f32x4*)(src + 12);
    const int r2 = t >> 4, c2 = (t & 15) * 8;
    *(f32x4*)&tl16[r2][c2]   = *(const f32x4*)(ws + WS_T + r2*C_ + c2);
    *(f32x4*)&tl16[r2][c2+4] = *(const f32x4*)(ws + WS_T + r2*C_ + c2 + 4);
    if (t < 32) *(f32x4*)&wcl[t*4] = *(const f32x4*)(W1 + 2*C_*C_ + t*4);
  }
  __syncthreads();

  // 1/max(||q||, eps) — 32 queries x 8 threads = 256 threads
  {
    const int q = t >> 3, c0 = (t & 7) * 16;
    float s = 0.f;
    #pragma unroll
    for (int m = 0; m < 16; ++m){ float v = qfs[q][c0+m]; s = fmaf(v, v, s); }
    s += __shfl_xor(s, 1); s += __shfl_xor(s, 2); s += __shfl_xor(s, 4);
    if ((t & 7) == 0) rqn[q] = 1.f / fmaxf(sqrtf(s), 1e-8f);
  }

  // A-fragments: group 0 = query fr, group 1 = query fr+16
  s16x8 qfrA[4], qfrB[4];
  #pragma unroll
  for (int ks = 0; ks < 4; ++ks){
    const int c0 = ks*32 + fg*8;
    f32x4 a = *(const f32x4*)&qfs[fr][c0];
    f32x4 b = *(const f32x4*)&qfs[fr][c0+4];
    s16x8 v;
    v[0]=f2bf(a[0]); v[1]=f2bf(a[1]); v[2]=f2bf(a[2]); v[3]=f2bf(a[3]);
    v[4]=f2bf(b[0]); v[5]=f2bf(b[1]); v[6]=f2bf(b[2]); v[7]=f2bf(b[3]);
    qfrA[ks] = v;
    f32x4 a2 = *(const f32x4*)&qfs[fr+16][c0];
    f32x4 b2x = *(const f32x4*)&qfs[fr+16][c0+4];
    s16x8 w;
    w[0]=f2bf(a2[0]); w[1]=f2bf(a2[1]); w[2]=f2bf(a2[2]); w[3]=f2bf(a2[3]);
    w[4]=f2bf(b2x[0]); w[5]=f2bf(b2x[1]); w[6]=f2bf(b2x[2]); w[7]=f2bf(b2x[3]);
    qfrB[ks] = w;
  }
  // B-fragments of W2 for this wave's two col-tiles
  s16x8 w2f[2][4];
  float b2v[2];
  #pragma unroll
  for (int j = 0; j < 2; ++j){
    const int tt = wv*2 + j;
    #pragma unroll
    for (int ks = 0; ks < 4; ++ks)
      w2f[j][ks] = *(const s16x8*)&pack[((tt*4 + ks)*64 + lane)*8];
    b2v[j] = b2[tt*16 + fr];
  }
  __syncthreads();   // rqn ready; all qfs reads done

  // qW = qf @ Wq for BOTH query groups : wave wv covers col-tiles wv*2, wv*2+1
  #pragma unroll
  for (int g = 0; g < 2; ++g){
    #pragma unroll
    for (int j = 0; j < 2; ++j){
      const int tt = wv*2 + j;
      f32x4 dq = {0.f,0.f,0.f,0.f};
      #pragma unroll
      for (int ks = 0; ks < 4; ++ks)
        dq = __builtin_amdgcn_mfma_f32_16x16x32_bf16(g ? qfrB[ks] : qfrA[ks],
               *(const s16x8*)&pack[16384 + ((tt*4 + ks)*64 + lane)*8], dq, 0,0,0);
      #pragma unroll
      for (int r = 0; r < 4; ++r) qw[g*16 + fg*4 + r][tt*16 + fr] = dq[r];
    }
  }
  // cos: wave 0 -> group 0 (q 0..15), wave 1 -> group 1 (q 16..31)
  if (wv < 2){
    f32x4 dc = {0.f,0.f,0.f,0.f};
    #pragma unroll
    for (int ks = 0; ks < 4; ++ks)
      dc = __builtin_amdgcn_mfma_f32_16x16x32_bf16(wv ? qfrB[ks] : qfrA[ks],
             *(const s16x8*)&pack[32768 + (ks*64 + lane)*8], dc, 0,0,0);
    #pragma unroll
    for (int r = 0; r < 4; ++r){
      const int q = wv*16 + fg*4 + r;
      const float cv = dc[r] * rqn[q];
      cosl[q][fr] = cv;
      if (qbase + q < NQ_)
        out_cos[(size_t)(qbase + q)*NC_ + fr] = cv;
    }
  }
  __syncthreads();   // qw, cosl ready; qfs dead -> hfrag live

  // phase-A constants: wave wv == k-step; lane -> (class fr, k-group fg)
  const int k0 = wv*32 + fg*8;
  const f32x4 t8a = *(const f32x4*)&tl16[fr][k0];
  const f32x4 t8b = *(const f32x4*)&tl16[fr][k0+4];
  const f32x4 w8a = *(const f32x4*)&wcl[k0];
  const f32x4 w8b = *(const f32x4*)&wcl[k0+4];

  #pragma unroll
  for (int chunk = 0; chunk < 8; ++chunk){
    const int q0 = chunk * 4;
    if (qbase + q0 >= NQ_) break;    // block-uniform tail cut (no barrier divergence)
    // phase A: H = relu(qW + t_n + cos*Wc) -> bf16 fragments
    #pragma unroll
    for (int qq = 0; qq < 4; ++qq){
      const int q = q0 + qq;
      f32x4 qa = *(const f32x4*)&qw[q][k0];     // broadcast within fg-group
      f32x4 qb = *(const f32x4*)&qw[q][k0+4];
      const float cv = cosl[q][fr];
      s16x8 hv;
      #pragma unroll
      for (int jj = 0; jj < 4; ++jj)
        hv[jj] = f2bf(fmaxf(fmaf(cv, w8a[jj], qa[jj] + t8a[jj]), 0.f));
      #pragma unroll
      for (int jj = 0; jj < 4; ++jj)
        hv[4+jj] = f2bf(fmaxf(fmaf(cv, w8b[jj], qb[jj] + t8b[jj]), 0.f));
      *(s16x8*)&hfrag[qq*2048 + wv*512 + lane*8] = hv;   // b128, conflict-free
    }
    __syncthreads();
    // phase B: sim = H @ W2 + b2 ; one ds_read set feeds both col-tiles
    #pragma unroll
    for (int qq = 0; qq < 4; ++qq){
      const short* hb = &hfrag[qq*2048 + lane*8];
      s16x8 a0 = *(const s16x8*)&hb[0];
      s16x8 a1 = *(const s16x8*)&hb[512];
      s16x8 a2 = *(const s16x8*)&hb[1024];
      s16x8 a3 = *(const s16x8*)&hb[1536];
      const size_t qout = (size_t)(qbase + q0 + qq) * (NC_*C_);
      #pragma unroll
      for (int j = 0; j < 2; ++j){
        f32x4 acc = {b2v[j], b2v[j], b2v[j], b2v[j]};
        acc = __builtin_amdgcn_mfma_f32_16x16x32_bf16(a0, w2f[j][0], acc, 0,0,0);
        acc = __builtin_amdgcn_mfma_f32_16x16x32_bf16(a1, w2f[j][1], acc, 0,0,0);
        acc = __builtin_amdgcn_mfma_f32_16x16x32_bf16(a2, w2f[j][2], acc, 0,0,0);
        acc = __builtin_amdgcn_mfma_f32_16x16x32_bf16(a3, w2f[j][3], acc, 0,0,0);
        const int ocol = (wv*2 + j)*16 + fr;
        #pragma unroll
        for (int r = 0; r < 4; ++r)
          out[qout + (fg*4 + r)*C_ + ocol] = acc[r];
      }
    }
    __syncthreads();
  }
}

extern "C" void kernel_launch(void* const* d_in, const int* in_sizes, int n_in,
                              void* d_out, int out_size, void* d_ws, size_t ws_size,
                              hipStream_t stream){
  const float* sf  = (const float*)d_in[0];
  const int*   lbl = (const int*)  d_in[1];
  const float* qf  = (const float*)d_in[2];
  const float* W1  = (const float*)d_in[3];
  const float* b1  = (const float*)d_in[4];
  const float* W2  = (const float*)d_in[5];
  const float* b2  = (const float*)d_in[6];
  float* ws  = (float*)d_ws;
  float* out = (float*)d_out;

  protoA<<<272, 256, 0, stream>>>(sf, lbl, W1, W2, ws);
  protoB<<<NC_, 512, 0, stream>>>(W1, b1, ws);
  fused_main<<<NBLK2, 256, 0, stream>>>(qf, W1, b2, ws, out);
}